// Round 4
// baseline (191.847 us; speedup 1.0000x reference)
//
#include <hip/hip_runtime.h>

#define N_NODES 50000
#define N_EDGES 800000
// IN=HID=64, OUT=16, N_RELS=16, N_BASES=4 (hard-coded below)

typedef __attribute__((ext_vector_type(8))) short bf16x8;
typedef __attribute__((ext_vector_type(4))) float f32x4;

// ---- bf16 helpers (RNE pack, shift-unpack) --------------------------------
__device__ __forceinline__ unsigned bf16rne(float x) {
  unsigned u = __float_as_uint(x);
  return (u + 0x7FFFu + ((u >> 16) & 1u)) >> 16;
}
__device__ __forceinline__ unsigned packbf2(float a, float b) {
  return bf16rne(a) | (bf16rne(b) << 16);
}
__device__ __forceinline__ float bflo(unsigned u) { return __uint_as_float(u << 16); }
__device__ __forceinline__ float bfhi(unsigned u) { return __uint_as_float(u & 0xFFFF0000u); }

// ===========================================================================
// Pure-streaming prep: feats -> bf16 pack; block 3125 builds bf16 B-matrices.
// ===========================================================================
__global__ __launch_bounds__(256) void k_pack(
    const float4* __restrict__ feats4, uint2* __restrict__ xbf,
    const float* __restrict__ bases1, const float* __restrict__ bases2,
    unsigned short* __restrict__ b1T, unsigned short* __restrict__ b2p) {
  if (blockIdx.x < 3125) {
    const int i = blockIdx.x * 256 + threadIdx.x;  // < 800000
    float4 v = feats4[i];
    xbf[i] = make_uint2(packbf2(v.x, v.y), packbf2(v.z, v.w));
  } else {
    for (int idx = threadIdx.x; idx < 64 * 256; idx += 256) {
      int o = idx >> 8, q = idx & 255;
      b1T[idx] = (unsigned short)bf16rne(bases1[q * 64 + o]);
    }
    for (int idx = threadIdx.x; idx < 64 * 64; idx += 256) {
      int j = idx >> 6, k = idx & 63;
      int o = j >> 2, b = j & 3;
      b2p[idx] = (unsigned short)bf16rne(bases2[b * 1024 + k * 16 + o]);
    }
  }
}

// ===========================================================================
// Block-local LDS counting sort, 2-D grid: 64 edge-chunks x 4 node-slices.
// rank[e] = chunk-local rank (uchar: per-(chunk,node) count <= ~10);
// bh[c][node] flushed coalesced (ushort).
// ===========================================================================
#define G_HIST 64
#define CHUNK (N_EDGES / G_HIST)   // 12500
#define NSLICE 4
#define HBINS (N_NODES / NSLICE)   // 12500 bins -> 50 KB LDS

__global__ __launch_bounds__(512) void k_hist(
    const int* __restrict__ dst, unsigned char* __restrict__ rank,
    unsigned short* __restrict__ bh) {  // [G_HIST][N_NODES]
  __shared__ int hist[HBINS];
  const int c = blockIdx.x & (G_HIST - 1);
  const int p = blockIdx.x >> 6;
  const int e0 = c * CHUNK;
  const int lo = p * HBINS;
  for (int i = threadIdx.x; i < HBINS; i += 512) hist[i] = 0;
  __syncthreads();
  for (int i = threadIdx.x; i < CHUNK; i += 512) {
    const int d = dst[e0 + i] - lo;
    if ((unsigned)d < (unsigned)HBINS)
      rank[e0 + i] = (unsigned char)atomicAdd(&hist[d], 1);
  }
  __syncthreads();
  for (int i = threadIdx.x; i < HBINS; i += 512)
    bh[(size_t)c * N_NODES + lo + i] = (unsigned short)hist[i];
}

// ===========================================================================
// Fused cross-chunk combine + hierarchical exclusive scan -> rowp.
// 98 blocks x 512 threads; LDS tile [64][512] ushort bridges the layout:
// global traffic coalesced uint2 both ways; per-node prefix runs in LDS.
// ===========================================================================
#define NB 512
__global__ __launch_bounds__(512) void k_scan1(
    unsigned short* __restrict__ bh,  // [G_HIST][N_NODES]
    int* __restrict__ rowp, int* __restrict__ bsum) {
  __shared__ unsigned short tile[G_HIST][NB];  // 64 KB
  __shared__ int wsum[8];
  const int tid = threadIdx.x;
  const int n0 = blockIdx.x * NB;
  for (int idx = tid; idx < G_HIST * (NB / 4); idx += 512) {
    const int c = idx >> 7, j = idx & 127;
    const int nloc = 4 * j;
    uint2 u = make_uint2(0u, 0u);
    if (n0 + nloc < N_NODES)  // N_NODES % 4 == 0: all-or-none per uint2
      u = *(const uint2*)(bh + (size_t)c * N_NODES + n0 + nloc);
    *(uint2*)&tile[c][nloc] = u;
  }
  __syncthreads();
  int s = 0;
  for (int c = 0; c < G_HIST; ++c) {
    const int cnt = tile[c][tid];
    tile[c][tid] = (unsigned short)s;
    s += cnt;
  }
  __syncthreads();
  for (int idx = tid; idx < G_HIST * (NB / 4); idx += 512) {
    const int c = idx >> 7, j = idx & 127;
    const int nloc = 4 * j;
    if (n0 + nloc < N_NODES)
      *(uint2*)(bh + (size_t)c * N_NODES + n0 + nloc) = *(uint2*)&tile[c][nloc];
  }
  const int lane = tid & 63, wid = tid >> 6;
  int v = (n0 + tid < N_NODES) ? s : 0;
  int incl = v;
#pragma unroll
  for (int off = 1; off < 64; off <<= 1) {
    int t = __shfl_up(incl, off, 64);
    if (lane >= off) incl += t;
  }
  if (lane == 63) wsum[wid] = incl;
  __syncthreads();
  if (tid < 8) {
    int wi = wsum[tid];
#pragma unroll
    for (int off = 1; off < 8; off <<= 1) {
      int t = __shfl_up(wi, off, 64);
      if (lane >= off) wi += t;
    }
    wsum[tid] = wi;
  }
  __syncthreads();
  int woff = (wid > 0) ? wsum[wid - 1] : 0;
  int incl_all = incl + woff;
  if (n0 + tid < N_NODES) rowp[n0 + tid + 1] = incl_all;
  if (tid == NB - 1) bsum[blockIdx.x] = incl_all;
}

__global__ __launch_bounds__(512) void k_scan3(int* __restrict__ rowp,
                                               const int* __restrict__ bsum) {
  __shared__ int s_off;
  const int tid = threadIdx.x;
  if (tid < 64) {
    int v = 0;
    for (int b = tid; b < (int)blockIdx.x; b += 64) v += bsum[b];
#pragma unroll
    for (int off = 32; off >= 1; off >>= 1) v += __shfl_down(v, off, 64);
    if (tid == 0) s_off = v;
  }
  __syncthreads();
  const int i = blockIdx.x * NB + tid;
  if (i < N_NODES) rowp[i + 1] += s_off;
  if (i == 0) rowp[0] = 0;
}

// ===========================================================================
// 4 B records: src(16b) | ety(4b) | norm 12-bit fixed-point.
// pos = rowp[dst] + bh[chunk][dst] + rank (chunk-local, uchar).
// ===========================================================================
__global__ __launch_bounds__(256) void k_scatter(
    const int* __restrict__ src, const int* __restrict__ dst,
    const int* __restrict__ ety, const float* __restrict__ enorm,
    const int* __restrict__ rowp, const unsigned char* __restrict__ rank,
    const unsigned short* __restrict__ bh, unsigned* __restrict__ s_edge) {
  int e = blockIdx.x * 256 + threadIdx.x;
  if (e >= N_EDGES) return;
  const int d = dst[e];
  const int b = e / CHUNK;
  const int pos = rowp[d] + (int)bh[(size_t)b * N_NODES + d] + (int)rank[e];
  unsigned nq = (unsigned)(enorm[e] * 4096.f + 0.5f);
  nq = nq > 4095u ? 4095u : nq;
  s_edge[pos] = (unsigned)src[e] | ((unsigned)ety[e] << 16) | (nq << 20);
}

#define NMSCALE (1.f / 4096.f)

// ===========================================================================
// Gather one node's u into a 2-SLAB MFMA A-tile (bf16), fp32 accumulate.
// Wave = node; eslot = lane>>4 owns a CONTIGUOUS quarter of the segment;
// ch4 = lane&15 (channels 4ch4..+3, 8 B load). Each batch issues 4
// independent rec loads, then 4 independent xv gathers -> 2 serialized
// round trips per batch (deg<=16: one batch) instead of 4-6 strided stalls.
// Padding uses rec=0 -> nm=0 (zero contribution, no divergence).
// ===========================================================================
#define ROWB 264
__device__ __forceinline__ void gather_node(
    const int* __restrict__ rowp, const unsigned* __restrict__ s_edge,
    const uint2* __restrict__ xv, const float4* __restrict__ coefLDS,
    unsigned short* __restrict__ uA,  // [2][16][ROWB]
    int node, int m, int lane) {
  const int eslot = lane >> 4, ch4 = lane & 15;
  const int beg = rowp[node], end = rowp[node + 1];
  const int qlen = (end - beg + 3) >> 2;
  int p = beg + eslot * qlen;
  const int pend = min(p + qlen, end);
  float4 a0 = {0, 0, 0, 0}, a1 = {0, 0, 0, 0}, a2 = {0, 0, 0, 0}, a3 = {0, 0, 0, 0};
  for (; p < pend; p += 4) {
    const int nb = pend - p;  // > 0
    unsigned rec[4];
#pragma unroll
    for (int t = 0; t < 4; ++t) rec[t] = (t < nb) ? s_edge[p + t] : 0u;
    uint2 xp[4];
#pragma unroll
    for (int t = 0; t < 4; ++t) xp[t] = xv[(rec[t] & 0xFFFF) * 16 + ch4];
#pragma unroll
    for (int t = 0; t < 4; ++t) {
      const float nm = (float)(rec[t] >> 20) * NMSCALE;  // 0 for padded
      const float4 c = coefLDS[(rec[t] >> 16) & 15];
      const float w0 = nm * c.x, w1 = nm * c.y, w2 = nm * c.z, w3 = nm * c.w;
      const float x0 = bflo(xp[t].x), x1 = bfhi(xp[t].x);
      const float x2 = bflo(xp[t].y), x3 = bfhi(xp[t].y);
      a0.x += w0 * x0; a0.y += w0 * x1; a0.z += w0 * x2; a0.w += w0 * x3;
      a1.x += w1 * x0; a1.y += w1 * x1; a1.z += w1 * x2; a1.w += w1 * x3;
      a2.x += w2 * x0; a2.y += w2 * x1; a2.z += w2 * x2; a2.w += w2 * x3;
      a3.x += w3 * x0; a3.y += w3 * x1; a3.z += w3 * x2; a3.w += w3 * x3;
    }
  }
  // Combine eslot pairs {e, e+2}: one butterfly stage (results on eslot 0,1).
#define RED1(x) x += __shfl_down(x, 32, 64)
  RED1(a0.x); RED1(a0.y); RED1(a0.z); RED1(a0.w);
  RED1(a1.x); RED1(a1.y); RED1(a1.z); RED1(a1.w);
  RED1(a2.x); RED1(a2.y); RED1(a2.z); RED1(a2.w);
  RED1(a3.x); RED1(a3.y); RED1(a3.z); RED1(a3.w);
#undef RED1
  if (eslot < 2) {
    unsigned short* row = uA + (eslot * 16 + m) * ROWB + 4 * ch4;
    *(uint2*)(row + 0 * 64) = make_uint2(packbf2(a0.x, a0.y), packbf2(a0.z, a0.w));
    *(uint2*)(row + 1 * 64) = make_uint2(packbf2(a1.x, a1.y), packbf2(a1.z, a1.w));
    *(uint2*)(row + 2 * 64) = make_uint2(packbf2(a2.x, a2.y), packbf2(a2.z, a2.w));
    *(uint2*)(row + 3 * 64) = make_uint2(packbf2(a3.x, a3.y), packbf2(a3.z, a3.w));
  }
}

// ===========================================================================
// Fused layer 1 + Y2 pre-transform: 16 nodes/block, 4 waves.
// ===========================================================================
__global__ __launch_bounds__(256) void k_l1_fused(
    const int* __restrict__ rowp, const unsigned* __restrict__ s_edge,
    const uint2* __restrict__ xbf, const float* __restrict__ coef1,
    const unsigned short* __restrict__ b1T,  // [64][256] bf16
    const float* __restrict__ bias1,         // [64]
    const unsigned short* __restrict__ b2p,  // [64][64] bf16
    uint2* __restrict__ y2bf) {              // [N][16] uint2 = [N][64] bf16
  __shared__ __align__(16) unsigned short uA[2 * 16 * ROWB];  // 16.5 KB
  __shared__ float coefs[64];
  __shared__ float cmat[16 * 68];  // 4.25 KB
  const int wid = threadIdx.x >> 6, lane = threadIdx.x & 63;
  if (threadIdx.x < 64) coefs[threadIdx.x] = coef1[threadIdx.x];
  __syncthreads();
  const int nbase = blockIdx.x * 16;
#pragma unroll
  for (int jn = 0; jn < 4; ++jn) {
    const int m = wid * 4 + jn;
    gather_node(rowp, s_edge, xbf, (const float4*)coefs, uA, nbase + m, m, lane);
  }
  __syncthreads();
  const int nloc = lane & 15, kgrp = lane >> 4;
  f32x4 acc1 = {0.f, 0.f, 0.f, 0.f};
#pragma unroll
  for (int ks = 0; ks < 8; ++ks) {
    const int k0 = ks * 32 + kgrp * 8;
    const bf16x8 b = *(const bf16x8*)&b1T[(wid * 16 + nloc) * 256 + k0];
    const bf16x8 aS0 = *(const bf16x8*)&uA[(0 * 16 + nloc) * ROWB + k0];
    acc1 = __builtin_amdgcn_mfma_f32_16x16x32_bf16(aS0, b, acc1, 0, 0, 0);
    const bf16x8 aS1 = *(const bf16x8*)&uA[(1 * 16 + nloc) * ROWB + k0];
    acc1 = __builtin_amdgcn_mfma_f32_16x16x32_bf16(aS1, b, acc1, 0, 0, 0);
  }
  {
    const int o = wid * 16 + nloc;
    const float bs = bias1[o];
#pragma unroll
    for (int r = 0; r < 4; ++r) {
      const int m = (lane >> 4) * 4 + r;
      cmat[m * 68 + o] = fmaxf(acc1[r] + bs, 0.f);
    }
  }
  __syncthreads();
  f32x4 acc2 = {0.f, 0.f, 0.f, 0.f};
#pragma unroll
  for (int ks = 0; ks < 2; ++ks) {
    const int k0 = ks * 32 + kgrp * 8;
    const float4 c0 = *(const float4*)&cmat[nloc * 68 + k0];
    const float4 c1 = *(const float4*)&cmat[nloc * 68 + k0 + 4];
    union { bf16x8 v; unsigned u[4]; } au;
    au.u[0] = packbf2(c0.x, c0.y); au.u[1] = packbf2(c0.z, c0.w);
    au.u[2] = packbf2(c1.x, c1.y); au.u[3] = packbf2(c1.z, c1.w);
    const bf16x8 b = *(const bf16x8*)&b2p[(wid * 16 + nloc) * 64 + k0];
    acc2 = __builtin_amdgcn_mfma_f32_16x16x32_bf16(au.v, b, acc2, 0, 0, 0);
  }
  __syncthreads();  // cmat reads done; reuse as Y2 staging
#pragma unroll
  for (int r = 0; r < 4; ++r) {
    const int m = (lane >> 4) * 4 + r;
    cmat[m * 68 + wid * 16 + nloc] = acc2[r];
  }
  __syncthreads();
  const int nl = threadIdx.x >> 4, c4 = threadIdx.x & 15;
  const float* cr = &cmat[nl * 68 + 4 * c4];
  y2bf[(size_t)(nbase + nl) * 16 + c4] =
      make_uint2(packbf2(cr[0], cr[1]), packbf2(cr[2], cr[3]));
}

// ===========================================================================
// Layer 2 (slim, widened): wave = 2 nodes; eslot = lane>>3 owns a CONTIGUOUS
// eighth of each node's segment; og = lane&7 (2 out-channels x 4 bases).
// Batch of 2: issue 4 independent recs (2 per node), then 4 y2v gathers,
// then compute -> 2 serialized round trips per wave in the common case.
// ===========================================================================
__global__ __launch_bounds__(256) void k_l2_gather(
    const int* __restrict__ rowp, const unsigned* __restrict__ s_edge,
    const uint4* __restrict__ y2v,   // [N][8] uint4
    const float* __restrict__ coef2, const float* __restrict__ bias2,
    float2* __restrict__ out) {      // [N][8] float2
  __shared__ float coefs[64];
  if (threadIdx.x < 64) coefs[threadIdx.x] = coef2[threadIdx.x];
  __syncthreads();
  const float4* coefv = (const float4*)coefs;
  const int wid = threadIdx.x >> 6, lane = threadIdx.x & 63;
  const int eslot = lane >> 3, og = lane & 7;
  const int nbase = blockIdx.x * 8 + wid * 2;

  float a0[2] = {0.f, 0.f}, a1[2] = {0.f, 0.f};
  int p[2], pend[2];
#pragma unroll
  for (int m = 0; m < 2; ++m) {
    const int beg = rowp[nbase + m], end = rowp[nbase + m + 1];
    const int qlen = (end - beg + 7) >> 3;
    p[m] = beg + eslot * qlen;
    pend[m] = min(p[m] + qlen, end);
  }
  while ((p[0] < pend[0]) | (p[1] < pend[1])) {
    unsigned rec[2][2] = {{0u, 0u}, {0u, 0u}};
#pragma unroll
    for (int m = 0; m < 2; ++m) {
      if (p[m] < pend[m]) rec[m][0] = s_edge[p[m]];
      if (p[m] + 1 < pend[m]) rec[m][1] = s_edge[p[m] + 1];
    }
    uint4 yp[2][2];
#pragma unroll
    for (int m = 0; m < 2; ++m)
#pragma unroll
      for (int t = 0; t < 2; ++t)
        yp[m][t] = y2v[(rec[m][t] & 0xFFFF) * 8 + og];
#pragma unroll
    for (int m = 0; m < 2; ++m)
#pragma unroll
      for (int t = 0; t < 2; ++t) {
        const float nm = (float)(rec[m][t] >> 20) * NMSCALE;  // 0 for padded
        const float4 c = coefv[(rec[m][t] >> 16) & 15];
        a0[m] += nm * (c.x * bflo(yp[m][t].x) + c.y * bfhi(yp[m][t].x) +
                       c.z * bflo(yp[m][t].y) + c.w * bfhi(yp[m][t].y));
        a1[m] += nm * (c.x * bflo(yp[m][t].z) + c.y * bfhi(yp[m][t].z) +
                       c.z * bflo(yp[m][t].w) + c.w * bfhi(yp[m][t].w));
      }
#pragma unroll
    for (int m = 0; m < 2; ++m) p[m] += 2;
  }
#pragma unroll
  for (int m = 0; m < 2; ++m) {
    a0[m] += __shfl_down(a0[m], 32, 64);
    a0[m] += __shfl_down(a0[m], 16, 64);
    a0[m] += __shfl_down(a0[m], 8, 64);
    a1[m] += __shfl_down(a1[m], 32, 64);
    a1[m] += __shfl_down(a1[m], 16, 64);
    a1[m] += __shfl_down(a1[m], 8, 64);
  }
  if (eslot == 0) {
    const float b0 = bias2[2 * og], b1 = bias2[2 * og + 1];
#pragma unroll
    for (int m = 0; m < 2; ++m) {
      out[(size_t)(nbase + m) * 8 + og] =
          make_float2(fmaxf(a0[m] + b0, 0.f), fmaxf(a1[m] + b1, 0.f));
    }
  }
}

extern "C" void kernel_launch(void* const* d_in, const int* in_sizes, int n_in,
                              void* d_out, int out_size, void* d_ws, size_t ws_size,
                              hipStream_t stream) {
  const float* feats  = (const float*)d_in[0];
  const int*   src    = (const int*)d_in[1];
  const int*   dst    = (const int*)d_in[2];
  const int*   etype  = (const int*)d_in[3];
  const float* enorm  = (const float*)d_in[4];
  const float* bases1 = (const float*)d_in[5];
  const float* coef1  = (const float*)d_in[6];
  const float* bias1  = (const float*)d_in[7];
  const float* bases2 = (const float*)d_in[8];
  const float* coef2  = (const float*)d_in[9];
  const float* bias2  = (const float*)d_in[10];

  // Workspace (~24 MB): xbf | y2bf | s_edge | bh | b1T | b2p | rowp | bsum
  //                     | rank (uchar)
  uint2* xbf    = (uint2*)d_ws;                       // N*16 uint2 (6.4 MB)
  uint2* y2bf   = xbf + (size_t)N_NODES * 16;         // N*16 uint2 (6.4 MB)
  unsigned* s_edge = (unsigned*)(y2bf + (size_t)N_NODES * 16);  // E uint (3.2 MB)
  unsigned short* bh = (unsigned short*)(s_edge + N_EDGES);  // 64*N ushort (6.4 MB)
  unsigned short* b1T = bh + (size_t)G_HIST * N_NODES;       // 16384 (32 KB)
  unsigned short* b2p = b1T + 64 * 256;               // 4096 (8 KB)
  int*   rowp   = (int*)(b2p + 64 * 64);              // N+1
  int*   bsum   = rowp + N_NODES + 1;                 // 98
  unsigned char* rank = (unsigned char*)(bsum + 128); // E uchar (0.8 MB)

  const int SCAN_BLKS = (N_NODES + NB - 1) / NB;  // 98

  k_pack<<<3126, 256, 0, stream>>>((const float4*)feats, xbf, bases1,
                                   bases2, b1T, b2p);
  k_hist<<<G_HIST * NSLICE, 512, 0, stream>>>(dst, rank, bh);
  k_scan1<<<SCAN_BLKS, 512, 0, stream>>>(bh, rowp, bsum);
  k_scan3<<<SCAN_BLKS, 512, 0, stream>>>(rowp, bsum);
  k_scatter<<<N_EDGES / 256, 256, 0, stream>>>(src, dst, etype, enorm,
                                               rowp, rank, bh, s_edge);
  k_l1_fused<<<N_NODES / 16, 256, 0, stream>>>(rowp, s_edge, xbf, coef1,
                                               b1T, bias1, b2p, y2bf);
  k_l2_gather<<<N_NODES / 8, 256, 0, stream>>>(rowp, s_edge,
                                               (const uint4*)y2bf, coef2,
                                               bias2, (float2*)d_out);
}

// Round 5
// 186.087 us; speedup vs baseline: 1.0310x; 1.0310x over previous
//
#include <hip/hip_runtime.h>

#define N_NODES 50000
#define N_EDGES 800000
// IN=HID=64, OUT=16, N_RELS=16, N_BASES=4 (hard-coded below)

typedef __attribute__((ext_vector_type(8))) short bf16x8;
typedef __attribute__((ext_vector_type(4))) float f32x4;

// ---- bf16 helpers (RNE pack, shift-unpack) --------------------------------
__device__ __forceinline__ unsigned bf16rne(float x) {
  unsigned u = __float_as_uint(x);
  return (u + 0x7FFFu + ((u >> 16) & 1u)) >> 16;
}
__device__ __forceinline__ unsigned packbf2(float a, float b) {
  return bf16rne(a) | (bf16rne(b) << 16);
}
__device__ __forceinline__ float bflo(unsigned u) { return __uint_as_float(u << 16); }
__device__ __forceinline__ float bfhi(unsigned u) { return __uint_as_float(u & 0xFFFF0000u); }

// ===========================================================================
// Geometry
// ===========================================================================
#define G_HIST 64
#define CHUNK (N_EDGES / G_HIST)   // 12500
#define NSLICE 4
#define HBINS (N_NODES / NSLICE)   // 12500 bins -> 50 KB LDS
#define NB 512
#define SCAN_BLKS ((N_NODES + NB - 1) / NB)  // 98
#define NHIST (G_HIST * NSLICE)    // 256 hist blocks
#define NPACK ((N_EDGES + 511) / 512)  // 1563 pack blocks (800000 float4s)

// ===========================================================================
// MERGED prep: hist blocks [0,256) | pack blocks [256,256+1563) | B-matrices.
// pack and hist are independent -> one launch, concurrent execution.
// ===========================================================================
__global__ __launch_bounds__(512) void k_prep(
    const float4* __restrict__ feats4, uint2* __restrict__ xbf,
    const float* __restrict__ bases1, const float* __restrict__ bases2,
    unsigned short* __restrict__ b1T, unsigned short* __restrict__ b2p,
    const int* __restrict__ dst, unsigned char* __restrict__ rank,
    unsigned short* __restrict__ bh) {  // [G_HIST][N_NODES]
  __shared__ int hist[HBINS];  // 50 KB (reserved by all blocks)
  const int bid = blockIdx.x;
  if (bid < NHIST) {
    // ---- block-local LDS counting sort: chunk c, node-slice p ----
    const int c = bid & (G_HIST - 1);
    const int p = bid >> 6;
    const int e0 = c * CHUNK;
    const int lo = p * HBINS;
    for (int i = threadIdx.x; i < HBINS; i += 512) hist[i] = 0;
    __syncthreads();
    for (int i = threadIdx.x; i < CHUNK; i += 512) {
      const int d = dst[e0 + i] - lo;
      if ((unsigned)d < (unsigned)HBINS)
        rank[e0 + i] = (unsigned char)atomicAdd(&hist[d], 1);
    }
    __syncthreads();
    for (int i = threadIdx.x; i < HBINS; i += 512)
      bh[(size_t)c * N_NODES + lo + i] = (unsigned short)hist[i];
  } else if (bid < NHIST + NPACK) {
    // ---- feats -> bf16 pack (pure streaming) ----
    const int i = (bid - NHIST) * 512 + threadIdx.x;
    if (i < N_EDGES) {  // 800000 float4 rows
      float4 v = feats4[i];
      xbf[i] = make_uint2(packbf2(v.x, v.y), packbf2(v.z, v.w));
    }
  } else {
    // ---- B-matrix prep ----
    for (int idx = threadIdx.x; idx < 64 * 256; idx += 512) {
      int o = idx >> 8, q = idx & 255;
      b1T[idx] = (unsigned short)bf16rne(bases1[q * 64 + o]);
    }
    for (int idx = threadIdx.x; idx < 64 * 64; idx += 512) {
      int j = idx >> 6, k = idx & 63;
      int o = j >> 2, b = j & 3;
      b2p[idx] = (unsigned short)bf16rne(bases2[b * 1024 + k * 16 + o]);
    }
  }
}

// ===========================================================================
// Cross-chunk combine + INTRA-BLOCK exclusive scan.
// rowp[n] = exclusive start of node n WITHIN its scan-block (partial);
// bsum[b] = block total. Consumers add prefix(bsum) themselves (no scan3).
// ===========================================================================
__global__ __launch_bounds__(512) void k_scan1(
    unsigned short* __restrict__ bh,  // [G_HIST][N_NODES]
    int* __restrict__ rowp, int* __restrict__ bsum) {
  __shared__ unsigned short tile[G_HIST][NB];  // 64 KB
  __shared__ int wsum[8];
  const int tid = threadIdx.x;
  const int n0 = blockIdx.x * NB;
  for (int idx = tid; idx < G_HIST * (NB / 4); idx += 512) {
    const int c = idx >> 7, j = idx & 127;
    const int nloc = 4 * j;
    uint2 u = make_uint2(0u, 0u);
    if (n0 + nloc < N_NODES)  // N_NODES % 4 == 0: all-or-none per uint2
      u = *(const uint2*)(bh + (size_t)c * N_NODES + n0 + nloc);
    *(uint2*)&tile[c][nloc] = u;
  }
  __syncthreads();
  int s = 0;
  for (int c = 0; c < G_HIST; ++c) {
    const int cnt = tile[c][tid];
    tile[c][tid] = (unsigned short)s;
    s += cnt;
  }
  __syncthreads();
  for (int idx = tid; idx < G_HIST * (NB / 4); idx += 512) {
    const int c = idx >> 7, j = idx & 127;
    const int nloc = 4 * j;
    if (n0 + nloc < N_NODES)
      *(uint2*)(bh + (size_t)c * N_NODES + n0 + nloc) = *(uint2*)&tile[c][nloc];
  }
  const int lane = tid & 63, wid = tid >> 6;
  const int v = (n0 + tid < N_NODES) ? s : 0;
  int incl = v;
#pragma unroll
  for (int off = 1; off < 64; off <<= 1) {
    int t = __shfl_up(incl, off, 64);
    if (lane >= off) incl += t;
  }
  if (lane == 63) wsum[wid] = incl;
  __syncthreads();
  if (tid < 8) {
    int wi = wsum[tid];
#pragma unroll
    for (int off = 1; off < 8; off <<= 1) {
      int t = __shfl_up(wi, off, 64);
      if (lane >= off) wi += t;
    }
    wsum[tid] = wi;
  }
  __syncthreads();
  const int woff = (wid > 0) ? wsum[wid - 1] : 0;
  const int incl_all = incl + woff;
  const int n = n0 + tid;
  if (n <= N_NODES) rowp[n] = incl_all - v;  // exclusive intra-block start
  if (tid == NB - 1) bsum[blockIdx.x] = incl_all;
}

// ---- per-wave prefix of bsum[0..b-1] (all lanes return the sum) -----------
__device__ __forceinline__ int prefix_bsum(const int* __restrict__ bsum,
                                           int b, int lane) {
  int v = 0;
  for (int k = lane; k < b; k += 64) v += bsum[k];
#pragma unroll
  for (int off = 32; off >= 1; off >>= 1) v += __shfl_xor(v, off, 64);
  return v;
}

// ===========================================================================
// 4 B records: src(16b) | ety(4b) | norm 12-bit fixed-point.
// pos = (rowp[d] + boff[d>>9]) + bh[chunk][d] + rank. boff built per block
// in LDS (98-entry Hillis-Steele scan, ~7 steps).
// ===========================================================================
__global__ __launch_bounds__(256) void k_scatter(
    const int* __restrict__ src, const int* __restrict__ dst,
    const int* __restrict__ ety, const float* __restrict__ enorm,
    const int* __restrict__ rowp, const unsigned char* __restrict__ rank,
    const unsigned short* __restrict__ bh, const int* __restrict__ bsum,
    unsigned* __restrict__ s_edge) {
  __shared__ int sb[128];
  const int tid = threadIdx.x;
  if (tid < 128) sb[tid] = (tid < SCAN_BLKS) ? bsum[tid] : 0;
  __syncthreads();
#pragma unroll
  for (int off = 1; off < 128; off <<= 1) {
    int t = 0;
    if (tid < 128 && tid >= off) t = sb[tid - off];
    __syncthreads();
    if (tid < 128) sb[tid] += t;
    __syncthreads();
  }
  const int e = blockIdx.x * 256 + tid;
  if (e >= N_EDGES) return;
  const int d = dst[e];
  const int b = e / CHUNK;
  const int blk = d >> 9;
  const int boff = blk ? sb[blk - 1] : 0;
  const int pos = rowp[d] + boff + (int)bh[(size_t)b * N_NODES + d] + (int)rank[e];
  unsigned nq = (unsigned)(enorm[e] * 4096.f + 0.5f);
  nq = nq > 4095u ? 4095u : nq;
  s_edge[pos] = (unsigned)src[e] | ((unsigned)ety[e] << 16) | (nq << 20);
}

#define NMSCALE (1.f / 4096.f)

// ===========================================================================
// Gather one node's u into a 2-SLAB MFMA A-tile (bf16), fp32 accumulate.
// Wave = node; eslot = lane>>4 owns a CONTIGUOUS quarter of [beg,end);
// ch4 = lane&15. Batch: 4 independent recs, then 4 independent xv gathers.
// ===========================================================================
#define ROWB 264
__device__ __forceinline__ void gather_node(
    const unsigned* __restrict__ s_edge, const uint2* __restrict__ xv,
    const float4* __restrict__ coefLDS,
    unsigned short* __restrict__ uA,  // [2][16][ROWB]
    int beg, int end, int m, int lane) {
  const int eslot = lane >> 4, ch4 = lane & 15;
  const int qlen = (end - beg + 3) >> 2;
  int p = beg + eslot * qlen;
  const int pend = min(p + qlen, end);
  float4 a0 = {0, 0, 0, 0}, a1 = {0, 0, 0, 0}, a2 = {0, 0, 0, 0}, a3 = {0, 0, 0, 0};
  for (; p < pend; p += 4) {
    const int nb = pend - p;  // > 0
    unsigned rec[4];
#pragma unroll
    for (int t = 0; t < 4; ++t) rec[t] = (t < nb) ? s_edge[p + t] : 0u;
    uint2 xp[4];
#pragma unroll
    for (int t = 0; t < 4; ++t) xp[t] = xv[(rec[t] & 0xFFFF) * 16 + ch4];
#pragma unroll
    for (int t = 0; t < 4; ++t) {
      const float nm = (float)(rec[t] >> 20) * NMSCALE;  // 0 for padded
      const float4 c = coefLDS[(rec[t] >> 16) & 15];
      const float w0 = nm * c.x, w1 = nm * c.y, w2 = nm * c.z, w3 = nm * c.w;
      const float x0 = bflo(xp[t].x), x1 = bfhi(xp[t].x);
      const float x2 = bflo(xp[t].y), x3 = bfhi(xp[t].y);
      a0.x += w0 * x0; a0.y += w0 * x1; a0.z += w0 * x2; a0.w += w0 * x3;
      a1.x += w1 * x0; a1.y += w1 * x1; a1.z += w1 * x2; a1.w += w1 * x3;
      a2.x += w2 * x0; a2.y += w2 * x1; a2.z += w2 * x2; a2.w += w2 * x3;
      a3.x += w3 * x0; a3.y += w3 * x1; a3.z += w3 * x2; a3.w += w3 * x3;
    }
  }
#define RED1(x) x += __shfl_down(x, 32, 64)
  RED1(a0.x); RED1(a0.y); RED1(a0.z); RED1(a0.w);
  RED1(a1.x); RED1(a1.y); RED1(a1.z); RED1(a1.w);
  RED1(a2.x); RED1(a2.y); RED1(a2.z); RED1(a2.w);
  RED1(a3.x); RED1(a3.y); RED1(a3.z); RED1(a3.w);
#undef RED1
  if (eslot < 2) {
    unsigned short* row = uA + (eslot * 16 + m) * ROWB + 4 * ch4;
    *(uint2*)(row + 0 * 64) = make_uint2(packbf2(a0.x, a0.y), packbf2(a0.z, a0.w));
    *(uint2*)(row + 1 * 64) = make_uint2(packbf2(a1.x, a1.y), packbf2(a1.z, a1.w));
    *(uint2*)(row + 2 * 64) = make_uint2(packbf2(a2.x, a2.y), packbf2(a2.z, a2.w));
    *(uint2*)(row + 3 * 64) = make_uint2(packbf2(a3.x, a3.y), packbf2(a3.z, a3.w));
  }
}

// ===========================================================================
// Fused layer 1 + Y2 pre-transform: 16 nodes/block, 4 waves.
// rowp is block-partial; each wave resolves boff via prefix_bsum (<=150 cy).
// ===========================================================================
__global__ __launch_bounds__(256) void k_l1_fused(
    const int* __restrict__ rowp, const int* __restrict__ bsum,
    const unsigned* __restrict__ s_edge,
    const uint2* __restrict__ xbf, const float* __restrict__ coef1,
    const unsigned short* __restrict__ b1T,  // [64][256] bf16
    const float* __restrict__ bias1,         // [64]
    const unsigned short* __restrict__ b2p,  // [64][64] bf16
    uint2* __restrict__ y2bf) {              // [N][16] uint2 = [N][64] bf16
  __shared__ __align__(16) unsigned short uA[2 * 16 * ROWB];  // 16.5 KB
  __shared__ float coefs[64];
  __shared__ float cmat[16 * 68];  // 4.25 KB
  const int wid = threadIdx.x >> 6, lane = threadIdx.x & 63;
  if (threadIdx.x < 64) coefs[threadIdx.x] = coef1[threadIdx.x];
  __syncthreads();
  const int nbase = blockIdx.x * 16;
  const int b0 = nbase >> 9;
  const int boff0 = prefix_bsum(bsum, b0, lane);
  const int bs0 = bsum[b0];
#pragma unroll
  for (int jn = 0; jn < 4; ++jn) {
    const int m = wid * 4 + jn;
    const int node = nbase + m;
    const int beg = rowp[node] + (((node >> 9) == b0) ? boff0 : boff0 + bs0);
    const int end = rowp[node + 1] + ((((node + 1) >> 9) == b0) ? boff0 : boff0 + bs0);
    gather_node(s_edge, xbf, (const float4*)coefs, uA, beg, end, m, lane);
  }
  __syncthreads();
  const int nloc = lane & 15, kgrp = lane >> 4;
  f32x4 acc1 = {0.f, 0.f, 0.f, 0.f};
#pragma unroll
  for (int ks = 0; ks < 8; ++ks) {
    const int k0 = ks * 32 + kgrp * 8;
    const bf16x8 b = *(const bf16x8*)&b1T[(wid * 16 + nloc) * 256 + k0];
    const bf16x8 aS0 = *(const bf16x8*)&uA[(0 * 16 + nloc) * ROWB + k0];
    acc1 = __builtin_amdgcn_mfma_f32_16x16x32_bf16(aS0, b, acc1, 0, 0, 0);
    const bf16x8 aS1 = *(const bf16x8*)&uA[(1 * 16 + nloc) * ROWB + k0];
    acc1 = __builtin_amdgcn_mfma_f32_16x16x32_bf16(aS1, b, acc1, 0, 0, 0);
  }
  {
    const int o = wid * 16 + nloc;
    const float bs = bias1[o];
#pragma unroll
    for (int r = 0; r < 4; ++r) {
      const int m = (lane >> 4) * 4 + r;
      cmat[m * 68 + o] = fmaxf(acc1[r] + bs, 0.f);
    }
  }
  __syncthreads();
  f32x4 acc2 = {0.f, 0.f, 0.f, 0.f};
#pragma unroll
  for (int ks = 0; ks < 2; ++ks) {
    const int k0 = ks * 32 + kgrp * 8;
    const float4 c0 = *(const float4*)&cmat[nloc * 68 + k0];
    const float4 c1 = *(const float4*)&cmat[nloc * 68 + k0 + 4];
    union { bf16x8 v; unsigned u[4]; } au;
    au.u[0] = packbf2(c0.x, c0.y); au.u[1] = packbf2(c0.z, c0.w);
    au.u[2] = packbf2(c1.x, c1.y); au.u[3] = packbf2(c1.z, c1.w);
    const bf16x8 b = *(const bf16x8*)&b2p[(wid * 16 + nloc) * 64 + k0];
    acc2 = __builtin_amdgcn_mfma_f32_16x16x32_bf16(au.v, b, acc2, 0, 0, 0);
  }
  __syncthreads();  // cmat reads done; reuse as Y2 staging
#pragma unroll
  for (int r = 0; r < 4; ++r) {
    const int m = (lane >> 4) * 4 + r;
    cmat[m * 68 + wid * 16 + nloc] = acc2[r];
  }
  __syncthreads();
  const int nl = threadIdx.x >> 4, c4 = threadIdx.x & 15;
  const float* cr = &cmat[nl * 68 + 4 * c4];
  y2bf[(size_t)(nbase + nl) * 16 + c4] =
      make_uint2(packbf2(cr[0], cr[1]), packbf2(cr[2], cr[3]));
}

// ===========================================================================
// Layer 2 (slim, widened): wave = 2 nodes; eslot = lane>>3 owns a CONTIGUOUS
// eighth of each node's segment; og = lane&7 (2 out-channels x 4 bases).
// ===========================================================================
__global__ __launch_bounds__(256) void k_l2_gather(
    const int* __restrict__ rowp, const int* __restrict__ bsum,
    const unsigned* __restrict__ s_edge,
    const uint4* __restrict__ y2v,   // [N][8] uint4
    const float* __restrict__ coef2, const float* __restrict__ bias2,
    float2* __restrict__ out) {      // [N][8] float2
  __shared__ float coefs[64];
  if (threadIdx.x < 64) coefs[threadIdx.x] = coef2[threadIdx.x];
  __syncthreads();
  const float4* coefv = (const float4*)coefs;
  const int wid = threadIdx.x >> 6, lane = threadIdx.x & 63;
  const int eslot = lane >> 3, og = lane & 7;
  const int nbase = blockIdx.x * 8 + wid * 2;
  const int b0 = nbase >> 9;
  const int boff0 = prefix_bsum(bsum, b0, lane);
  const int bs0 = bsum[b0];

  float a0[2] = {0.f, 0.f}, a1[2] = {0.f, 0.f};
  int p[2], pend[2];
#pragma unroll
  for (int m = 0; m < 2; ++m) {
    const int node = nbase + m;
    const int beg = rowp[node] + (((node >> 9) == b0) ? boff0 : boff0 + bs0);
    const int end = rowp[node + 1] + ((((node + 1) >> 9) == b0) ? boff0 : boff0 + bs0);
    const int qlen = (end - beg + 7) >> 3;
    p[m] = beg + eslot * qlen;
    pend[m] = min(p[m] + qlen, end);
  }
  while ((p[0] < pend[0]) | (p[1] < pend[1])) {
    unsigned rec[2][2] = {{0u, 0u}, {0u, 0u}};
#pragma unroll
    for (int m = 0; m < 2; ++m) {
      if (p[m] < pend[m]) rec[m][0] = s_edge[p[m]];
      if (p[m] + 1 < pend[m]) rec[m][1] = s_edge[p[m] + 1];
    }
    uint4 yp[2][2];
#pragma unroll
    for (int m = 0; m < 2; ++m)
#pragma unroll
      for (int t = 0; t < 2; ++t)
        yp[m][t] = y2v[(rec[m][t] & 0xFFFF) * 8 + og];
#pragma unroll
    for (int m = 0; m < 2; ++m)
#pragma unroll
      for (int t = 0; t < 2; ++t) {
        const float nm = (float)(rec[m][t] >> 20) * NMSCALE;  // 0 for padded
        const float4 c = coefv[(rec[m][t] >> 16) & 15];
        a0[m] += nm * (c.x * bflo(yp[m][t].x) + c.y * bfhi(yp[m][t].x) +
                       c.z * bflo(yp[m][t].y) + c.w * bfhi(yp[m][t].y));
        a1[m] += nm * (c.x * bflo(yp[m][t].z) + c.y * bfhi(yp[m][t].z) +
                       c.z * bflo(yp[m][t].w) + c.w * bfhi(yp[m][t].w));
      }
#pragma unroll
    for (int m = 0; m < 2; ++m) p[m] += 2;
  }
#pragma unroll
  for (int m = 0; m < 2; ++m) {
    a0[m] += __shfl_down(a0[m], 32, 64);
    a0[m] += __shfl_down(a0[m], 16, 64);
    a0[m] += __shfl_down(a0[m], 8, 64);
    a1[m] += __shfl_down(a1[m], 32, 64);
    a1[m] += __shfl_down(a1[m], 16, 64);
    a1[m] += __shfl_down(a1[m], 8, 64);
  }
  if (eslot == 0) {
    const float b0s = bias2[2 * og], b1s = bias2[2 * og + 1];
#pragma unroll
    for (int m = 0; m < 2; ++m) {
      out[(size_t)(nbase + m) * 8 + og] =
          make_float2(fmaxf(a0[m] + b0s, 0.f), fmaxf(a1[m] + b1s, 0.f));
    }
  }
}

extern "C" void kernel_launch(void* const* d_in, const int* in_sizes, int n_in,
                              void* d_out, int out_size, void* d_ws, size_t ws_size,
                              hipStream_t stream) {
  const float* feats  = (const float*)d_in[0];
  const int*   src    = (const int*)d_in[1];
  const int*   dst    = (const int*)d_in[2];
  const int*   etype  = (const int*)d_in[3];
  const float* enorm  = (const float*)d_in[4];
  const float* bases1 = (const float*)d_in[5];
  const float* coef1  = (const float*)d_in[6];
  const float* bias1  = (const float*)d_in[7];
  const float* bases2 = (const float*)d_in[8];
  const float* coef2  = (const float*)d_in[9];
  const float* bias2  = (const float*)d_in[10];

  // Workspace (~24 MB): xbf | y2bf | s_edge | bh | b1T | b2p | rowp | bsum
  //                     | rank (uchar)
  uint2* xbf    = (uint2*)d_ws;                       // N*16 uint2 (6.4 MB)
  uint2* y2bf   = xbf + (size_t)N_NODES * 16;         // N*16 uint2 (6.4 MB)
  unsigned* s_edge = (unsigned*)(y2bf + (size_t)N_NODES * 16);  // E uint (3.2 MB)
  unsigned short* bh = (unsigned short*)(s_edge + N_EDGES);  // 64*N ushort (6.4 MB)
  unsigned short* b1T = bh + (size_t)G_HIST * N_NODES;       // 16384 (32 KB)
  unsigned short* b2p = b1T + 64 * 256;               // 4096 (8 KB)
  int*   rowp   = (int*)(b2p + 64 * 64);              // N+1
  int*   bsum   = rowp + N_NODES + 1;                 // 98 (pad 128)
  unsigned char* rank = (unsigned char*)(bsum + 128); // E uchar (0.8 MB)

  k_prep<<<NHIST + NPACK + 1, 512, 0, stream>>>(
      (const float4*)feats, xbf, bases1, bases2, b1T, b2p, dst, rank, bh);
  k_scan1<<<SCAN_BLKS, 512, 0, stream>>>(bh, rowp, bsum);
  k_scatter<<<(N_EDGES + 255) / 256, 256, 0, stream>>>(
      src, dst, etype, enorm, rowp, rank, bh, bsum, s_edge);
  k_l1_fused<<<N_NODES / 16, 256, 0, stream>>>(rowp, bsum, s_edge, xbf, coef1,
                                               b1T, bias1, b2p, y2bf);
  k_l2_gather<<<N_NODES / 8, 256, 0, stream>>>(rowp, bsum, s_edge,
                                               (const uint4*)y2bf, coef2,
                                               bias2, (float2*)d_out);
}